// Round 15
// baseline (184.016 us; speedup 1.0000x reference)
//
#include <hip/hip_runtime.h>
#include <hip/hip_bf16.h>
#include <stdint.h>

typedef __bf16 bf16x8 __attribute__((ext_vector_type(8)));
typedef __bf16 bf16x4 __attribute__((ext_vector_type(4)));
typedef float  f32x4  __attribute__((ext_vector_type(4)));
typedef unsigned int u32x4 __attribute__((ext_vector_type(4)));

#define D_MODEL 1024
#define NUM_HEADS 16
#define D_K 64
#define BATCH 2
#define SEQ 2048
#define M_TOTAL (BATCH * SEQ)   // 4096

// 0.125 (1/sqrt(64)) * log2(e): folded into Q at the qkv epilogue so the
// attention softmax is a bare exp2 (v_exp_f32), no per-element scale mul.
#define Q_SCALE 0.18033688011112042f

static __device__ __forceinline__ bf16x8 load8(const __bf16* p) {
    return *reinterpret_cast<const bf16x8*>(p);
}

#define MFMA16(a, b, c) __builtin_amdgcn_mfma_f32_16x16x32_bf16((a), (b), (c), 0, 0, 0)

// Async global->LDS, 16B per lane. LDS dest = wave-uniform base + lane*16.
static __device__ __forceinline__ void gload16(const void* g, const void* lds) {
    __builtin_amdgcn_global_load_lds(
        (const __attribute__((address_space(1))) uint32_t*)g,
        (__attribute__((address_space(3))) uint32_t*)lds,
        16, 0, 0);
}

// Pack two f32 -> one u32 of 2 bf16 (lo = first arg). No builtin on gfx950.
static __device__ __forceinline__ uint32_t cvtpk(float lo, float hi) {
    uint32_t r;
    asm("v_cvt_pk_bf16_f32 %0, %1, %2" : "=v"(r) : "v"(lo), "v"(hi));
    return r;
}
// CDNA4 zip semantics ("DST rows 2:3 <-> SRC rows 0:1", rows = 16 lanes):
//   swap32: a' = (a@q0, a@q1, b@q0, b@q1), b' = (a@q2, a@q3, b@q2, b@q3)
static __device__ __forceinline__ void swap32(uint32_t& a, uint32_t& b) {
    asm("v_permlane32_swap_b32 %0, %1" : "+v"(a), "+v"(b));
}
// swap16 ("DST odd rows <-> SRC even rows"):
//   a' = (a@q0, b@q0, a@q2, b@q2), b' = (a@q1, b@q1, a@q3, b@q3)
static __device__ __forceinline__ void swap16(uint32_t& a, uint32_t& b) {
    asm("v_permlane16_swap_b32 %0, %1" : "+v"(a), "+v"(b));
}

// ---------------------------------------------------------------------------
// One launch: x (2048 blocks) + 4 weight matrices (512 blocks each) fp32->bf16.
// ---------------------------------------------------------------------------
__global__ __launch_bounds__(256) void convert_all(
    const float* __restrict__ X,
    const float* __restrict__ Wq, const float* __restrict__ Wk,
    const float* __restrict__ Wv, const float* __restrict__ Wo,
    __bf16* __restrict__ xb,
    __bf16* __restrict__ dq, __bf16* __restrict__ dk,
    __bf16* __restrict__ dv, __bf16* __restrict__ dw)
{
    const float* src; __bf16* dst; size_t idx;
    if (blockIdx.x < 2048) {
        src = X; dst = xb;
        idx = (size_t)blockIdx.x * 256 + threadIdx.x;
    } else {
        const int wb  = blockIdx.x - 2048;
        const int sel = wb >> 9;
        src = (sel == 0) ? Wq : (sel == 1) ? Wk : (sel == 2) ? Wv : Wo;
        dst = (sel == 0) ? dq : (sel == 1) ? dk : (sel == 2) ? dv : dw;
        idx = (size_t)(wb & 511) * 256 + threadIdx.x;
    }
    const f32x4 a = *reinterpret_cast<const f32x4*>(src + idx * 8);
    const f32x4 b = *reinterpret_cast<const f32x4*>(src + idx * 8 + 4);
    bf16x8 r;
#pragma unroll
    for (int e = 0; e < 4; e++) { r[e] = (__bf16)a[e]; r[4 + e] = (__bf16)b[e]; }
    *reinterpret_cast<bf16x8*>(dst + idx * 8) = r;
}

// ---------------------------------------------------------------------------
// QKV GEMM (R16 config): 128x128 tile, BK=64, swizzled gload16 staging,
// double-buffered prefetch loop (one barrier per K-step, next tile's loads
// in flight through compute). LDS 64 KB -> 2 blocks/CU. Q output pre-scaled
// by Q_SCALE. V transposed through LDS -> V^T. grid = (32, 24), block = 256.
// ---------------------------------------------------------------------------
__global__ __launch_bounds__(256) void qkv_kernel(
    const __bf16* __restrict__ Xb,
    const __bf16* __restrict__ Wqb,
    const __bf16* __restrict__ Wkb,
    const __bf16* __restrict__ Wvb,
    __bf16* __restrict__ Qb,
    __bf16* __restrict__ Kb,
    __bf16* __restrict__ Vtg)
{
    __shared__ alignas(16) char smem[65536];   // A[2]16K + B[2]16K; V scratch 34K
    __bf16* As0 = (__bf16*)smem;               // [2][128*64], chunk-swizzled
    __bf16* Bs0 = As0 + 2 * 128 * 64;

    const int lane = threadIdx.x & 63;
    const int wid  = threadIdx.x >> 6;
    const int m    = lane & 15;
    const int quad = lane >> 4;
    const int wrow = wid >> 1, wcol = wid & 1;
    const int row0 = blockIdx.x * 128;
    const int col0 = blockIdx.y * 128;
    const int wsel = col0 >> 10;
    const int lcol0 = col0 & 1023;

    const __bf16* W = (wsel == 0) ? Wqb : (wsel == 1) ? Wkb : Wvb;

    // staging: 128x64 A-tile + 128x64 B-tile into buffer `buf`
    auto stage = [&](int k0, int buf) {
#pragma unroll
        for (int i = 0; i < 4; i++) {
            const int slot = wid * 256 + i * 64 + lane;
            const int row  = slot >> 3;
            const int cg   = (slot & 7) ^ (row & 7);
            gload16(Xb + (size_t)(row0 + row) * D_MODEL + k0 + cg * 8,
                    (const char*)(As0 + buf * 8192) + (size_t)(wid * 256 + i * 64) * 16);
            gload16(W + (size_t)(lcol0 + row) * D_MODEL + k0 + cg * 8,
                    (const char*)(Bs0 + buf * 8192) + (size_t)(wid * 256 + i * 64) * 16);
        }
    };

    f32x4 acc[4][4];
#pragma unroll
    for (int i = 0; i < 4; i++)
#pragma unroll
        for (int j = 0; j < 4; j++) acc[i][j] = (f32x4){0.f, 0.f, 0.f, 0.f};

    stage(0, 0);
    int cur = 0;
#pragma unroll 1
    for (int k0 = 0; k0 < D_MODEL; k0 += 64) {
        __syncthreads();                       // buffer `cur` staged
        if (k0 + 64 < D_MODEL) stage(k0 + 64, cur ^ 1);   // in flight through
                                                          // compute below
        const __bf16* As = As0 + cur * 8192;
        const __bf16* Bs = Bs0 + cur * 8192;

        bf16x8 a2[2][4], b2[2][4];
#pragma unroll
        for (int ks = 0; ks < 2; ks++) {
#pragma unroll
            for (int i = 0; i < 4; i++) {
                const int rA = wrow * 64 + i * 16 + m;
                a2[ks][i] = load8(As + rA * 64 + (((ks * 4 + quad) ^ (rA & 7)) * 8));
                const int rB = wcol * 64 + i * 16 + m;
                b2[ks][i] = load8(Bs + rB * 64 + (((ks * 4 + quad) ^ (rB & 7)) * 8));
            }
        }
#pragma unroll
        for (int ks = 0; ks < 2; ks++)
#pragma unroll
            for (int i = 0; i < 4; i++)
#pragma unroll
                for (int j = 0; j < 4; j++)
                    acc[i][j] = MFMA16(a2[ks][i], b2[ks][j], acc[i][j]);
        cur ^= 1;
    }
    __syncthreads();   // all LDS reads done before V-path smem reuse

    if (wsel < 2) {
        // Q (pre-scaled) / K: [bh][s][dk]
        __bf16* Out = wsel ? Kb : Qb;
        const float sc = wsel ? 1.f : Q_SCALE;
#pragma unroll
        for (int i = 0; i < 4; i++) {
#pragma unroll
            for (int r = 0; r < 4; r++) {
                const int R  = row0 + wrow * 64 + i * 16 + quad * 4 + r;
                const int bb = R >> 11;
                const int s  = R & (SEQ - 1);
#pragma unroll
                for (int j = 0; j < 4; j++) {
                    const int e  = lcol0 + wcol * 64 + j * 16 + m;
                    const int h  = e >> 6;
                    const int dk = e & (D_K - 1);
                    Out[((size_t)(bb * NUM_HEADS + h) * SEQ + s) * D_K + dk] =
                        (__bf16)(acc[i][j][r] * sc);
                }
            }
        }
    } else {
        // V: transpose tile through LDS, store coalesced V^T rows.
        __bf16* Ls = (__bf16*)smem;   // [128][136]
#pragma unroll
        for (int i = 0; i < 4; i++)
#pragma unroll
            for (int r = 0; r < 4; r++)
#pragma unroll
                for (int j = 0; j < 4; j++)
                    Ls[(wcol * 64 + j * 16 + m) * 136 +
                       wrow * 64 + i * 16 + quad * 4 + r] = (__bf16)acc[i][j][r];
        __syncthreads();
        const int bb   = row0 >> 11;
        const int sloc = row0 & (SEQ - 1);
#pragma unroll
        for (int i = 0; i < 8; i++) {
            const int c   = i * 256 + threadIdx.x;
            const int dkl = c >> 4;
            const int sc  = c & 15;
            const bf16x8 v = load8(Ls + dkl * 136 + sc * 8);
            const int e  = lcol0 + dkl;
            const int h  = e >> 6;
            const int dk = e & (D_K - 1);
            const int bh = bb * NUM_HEADS + h;
            *reinterpret_cast<bf16x8*>(
                Vtg + ((size_t)bh * D_K + dk) * SEQ + sloc + sc * 8) = v;
        }
    }
}

// ---------------------------------------------------------------------------
// Flash attention, causal (R22 configuration -- session-best total 177.9 us,
// locked in as the final kernel): 8-WAVE BLOCKS (512 threads), QBLK=128,
// each wave owns 16 q-rows (per-wave inner code identical to the proven R16
// kernel). One 64-key K/V tile staged per block-tile serves 8 waves. grid
// (32 bh, 16 strips) = 512 blocks = 2 blocks/CU = 16 waves/CU. Causal:
// wave's diagonal tile myDiag = q0>>6; waves skip compute (never the
// barrier) past their diagonal. Staging = 1 K-load + 1 V-load per thread.
// Register-resident P (zip-permlane), ones-MFMA row sums.
// ---------------------------------------------------------------------------
__global__ __launch_bounds__(512) void attn_kernel(
    const __bf16* __restrict__ Qb,
    const __bf16* __restrict__ Kb,
    const __bf16* __restrict__ Vtg,
    __bf16* __restrict__ Cc)
{
    __shared__ alignas(16) __bf16 Ks[2][64 * 64];  // ping-pong, 16 KB
    __shared__ alignas(16) __bf16 Vt[2][64 * 64];  // ping-pong, 16 KB

    const int lane = threadIdx.x & 63;
    const int wid  = threadIdx.x >> 6;             // 0..7
    const int m    = lane & 15;
    const int quad = lane >> 4;
    const int bh   = blockIdx.x;
    const int b    = bh >> 4;
    const int h    = bh & (NUM_HEADS - 1);
    const int sp   = 15 - blockIdx.y;              // 128-row strip, big first

    const __bf16* Qp = Qb  + (size_t)bh * SEQ * D_K;
    const __bf16* Kp = Kb  + (size_t)bh * SEQ * D_K;
    const __bf16* Vp = Vtg + (size_t)bh * D_K * SEQ;

    // staging: 64x64 K tile + 64x64 V^T tile; 512 threads cover each 8 KB
    // tile in ONE gload16 per thread per operand.
    auto stage = [&](int k0, int buf) {
        const int slot = wid * 64 + lane;
        const int row  = slot >> 3;
        const int cg   = (slot & 7) ^ (row & 7);
        gload16(Kp + (size_t)(k0 + row) * D_K + cg * 8,
                (const char*)&Ks[buf][0] + (size_t)slot * 16);
        gload16(Vp + (size_t)row * SEQ + k0 + cg * 8,
                (const char*)&Vt[buf][0] + (size_t)slot * 16);
    };

    bf16x8 vone;
#pragma unroll
    for (int e = 0; e < 8; e++) vone[e] = (__bf16)1.0f;

    const int q0     = sp * 128 + wid * 16;        // this wave's 16 q rows
    const int myDiag = q0 >> 6;                    // wave's diagonal tile
    const int T      = 2 * sp + 2;                 // tiles for this strip

    const bf16x8 qB0 = load8(Qp + (size_t)(q0 + m) * D_K + quad * 8);
    const bf16x8 qB1 = load8(Qp + (size_t)(q0 + m) * D_K + 32 + quad * 8);

    f32x4 oacc[4];
#pragma unroll
    for (int c = 0; c < 4; c++) oacc[c] = (f32x4){0.f, 0.f, 0.f, 0.f};
    f32x4 accL = (f32x4){0.f, 0.f, 0.f, 0.f};      // l for q = q0+quad*4+r

    stage(0, 0);
    int cur = 0;
#pragma unroll 1
    for (int t = 0; t < T; t++) {
        __syncthreads();             // tile t's staging complete (all waves)
        if (t + 1 < T) stage((t + 1) * 64, cur ^ 1);   // prefetch: in flight
                                                       // through compute below
        if (t <= myDiag) {
            const bool diag = (t == myDiag);
            const int  k0   = t * 64;
            const __bf16* Kc = &Ks[cur][0];
            const __bf16* Vc = &Vt[cur][0];

            // ---- S^T = K Q^T (rows=keys, cols=q); exp2; pack to bf16.
            // Lane (m,quad) produces keys {kb*16+quad*4 .. +3} for q=q0+m:
            // w0[kb] = keys {4*quad, 4*quad+1}, w1[kb] = {+2, +3}.
            uint32_t w0[4], w1[4];
#pragma unroll
            for (int kb = 0; kb < 4; kb++) {
                const int rK = kb * 16 + m;
                const bf16x8 kfA = load8(Kc + rK * 64 + ((quad ^ (rK & 7)) * 8));
                const bf16x8 kfB = load8(Kc + rK * 64 + (((quad + 4) ^ (rK & 7)) * 8));
                f32x4 st = (f32x4){0.f, 0.f, 0.f, 0.f};
                st = MFMA16(kfA, qB0, st);
                st = MFMA16(kfB, qB1, st);
                const int q    = q0 + m;
                const int keyb = k0 + kb * 16 + quad * 4;
                float ex[4];
#pragma unroll
                for (int r = 0; r < 4; r++) {
                    float e = __builtin_amdgcn_exp2f(st[r]);
                    if (diag) e = (keyb + r <= q) ? e : 0.f;
                    ex[r] = e;
                }
                w0[kb] = cvtpk(ex[0], ex[1]);
                w1[kb] = cvtpk(ex[2], ex[3]);
            }

            // ---- redistribute to A-fragments (keys 8*quad..+7 per lane).
            // Zip semantics, verified key-by-key:
            //   (X=w[lo], Y=w[hi]); swap32; swap16 => X=word j, Y=word j+2.
            uint32_t pa0 = w0[0], pa2 = w0[1]; swap32(pa0, pa2); swap16(pa0, pa2);
            uint32_t pa1 = w1[0], pa3 = w1[1]; swap32(pa1, pa3); swap16(pa1, pa3);
            uint32_t pb0 = w0[2], pb2 = w0[3]; swap32(pb0, pb2); swap16(pb0, pb2);
            uint32_t pb1 = w1[2], pb3 = w1[3]; swap32(pb1, pb3); swap16(pb1, pb3);
            const u32x4 ua = (u32x4){pa0, pa1, pa2, pa3};
            const u32x4 ub = (u32x4){pb0, pb1, pb2, pb3};
            const bf16x8 pfA = __builtin_bit_cast(bf16x8, ua);
            const bf16x8 pfB = __builtin_bit_cast(bf16x8, ub);

            // ---- row-sum via ones-MFMA: accL[r] = sum_k P[q=quad*4+r][k]
            accL = MFMA16(pfA, vone, accL);
            accL = MFMA16(pfB, vone, accL);

            // ---- P.V ----
#pragma unroll
            for (int c = 0; c < 4; c++) {
                const int rV = c * 16 + m;
                const bf16x8 vfA = load8(Vc + rV * 64 + ((quad ^ (rV & 7)) * 8));
                const bf16x8 vfB = load8(Vc + rV * 64 + (((quad + 4) ^ (rV & 7)) * 8));
                oacc[c] = MFMA16(pfA, vfA, oacc[c]);
                oacc[c] = MFMA16(pfB, vfB, oacc[c]);
            }
        }
        cur ^= 1;
    }

    // ---- epilogue: l is already per-register in accL ----
#pragma unroll
    for (int r = 0; r < 4; r++) {
        const float inv = 1.f / accL[r];
        const int srow = q0 + quad * 4 + r;
#pragma unroll
        for (int c = 0; c < 4; c++) {
            const size_t o2 = ((size_t)(b * SEQ + srow)) * D_MODEL + h * D_K + c * 16 + m;
            Cc[o2] = (__bf16)(oacc[c][r] * inv);
        }
    }
}

// ---------------------------------------------------------------------------
// Output projection (R16 config): Out = Cc * Wo^T + bo (fp32). 64x64 tile,
// grid (64,16) = 1024 blocks = 4/CU, double-buffered prefetch loop (one
// barrier per K-step), both operands via gload16 (bf16).
// ---------------------------------------------------------------------------
__global__ __launch_bounds__(256) void oproj_kernel(
    const __bf16* __restrict__ Cc,
    const __bf16* __restrict__ Wob,
    const float* __restrict__ bo,
    float* __restrict__ Out)
{
    __shared__ alignas(16) __bf16 As[2][64 * 64];  // ping-pong, 8 KB each
    __shared__ alignas(16) __bf16 Bs[2][64 * 64];  // ping-pong, 8 KB each

    const int lane = threadIdx.x & 63;
    const int wid  = threadIdx.x >> 6;
    const int m    = lane & 15;
    const int quad = lane >> 4;
    const int wrow = wid >> 1, wcol = wid & 1;
    const int row0 = blockIdx.x * 64;
    const int col0 = blockIdx.y * 64;

    auto stage = [&](int k0, int buf) {
#pragma unroll
        for (int i = 0; i < 2; i++) {
            const int slot = wid * 128 + i * 64 + lane;
            const int row  = slot >> 3;
            const int cg   = (slot & 7) ^ (row & 7);
            gload16(Cc + (size_t)(row0 + row) * D_MODEL + k0 + cg * 8,
                    (const char*)&As[buf][0] + (size_t)slot * 16);
            gload16(Wob + (size_t)(col0 + row) * D_MODEL + k0 + cg * 8,
                    (const char*)&Bs[buf][0] + (size_t)slot * 16);
        }
    };

    f32x4 acc[2][2];
#pragma unroll
    for (int i = 0; i < 2; i++)
#pragma unroll
        for (int j = 0; j < 2; j++) acc[i][j] = (f32x4){0.f, 0.f, 0.f, 0.f};

    stage(0, 0);
    int cur = 0;
#pragma unroll 1
    for (int k0 = 0; k0 < D_MODEL; k0 += 64) {
        __syncthreads();                       // buffer `cur` staged
        if (k0 + 64 < D_MODEL) stage(k0 + 64, cur ^ 1);

        bf16x8 a2[2][2], b2[2][2];
#pragma unroll
        for (int ks = 0; ks < 2; ks++) {
#pragma unroll
            for (int i = 0; i < 2; i++) {
                const int rA = wrow * 32 + i * 16 + m;
                a2[ks][i] = load8(&As[cur][0] + rA * 64 + (((ks * 4 + quad) ^ (rA & 7)) * 8));
                const int rB = wcol * 32 + i * 16 + m;
                b2[ks][i] = load8(&Bs[cur][0] + rB * 64 + (((ks * 4 + quad) ^ (rB & 7)) * 8));
            }
        }
#pragma unroll
        for (int ks = 0; ks < 2; ks++)
#pragma unroll
            for (int i = 0; i < 2; i++)
#pragma unroll
                for (int j = 0; j < 2; j++)
                    acc[i][j] = MFMA16(a2[ks][i], b2[ks][j], acc[i][j]);
        cur ^= 1;
    }

#pragma unroll
    for (int i = 0; i < 2; i++) {
#pragma unroll
        for (int r = 0; r < 4; r++) {
            const int R = row0 + wrow * 32 + i * 16 + quad * 4 + r;
#pragma unroll
            for (int j = 0; j < 2; j++) {
                const int E = col0 + wcol * 32 + j * 16 + m;
                Out[(size_t)R * D_MODEL + E] = acc[i][j][r] + bo[E];
            }
        }
    }
}

// ---------------------------------------------------------------------------
extern "C" void kernel_launch(void* const* d_in, const int* in_sizes, int n_in,
                              void* d_out, int out_size, void* d_ws, size_t ws_size,
                              hipStream_t stream) {
    const float* x  = (const float*)d_in[0];
    const float* Wq = (const float*)d_in[1];
    const float* Wk = (const float*)d_in[2];
    const float* Wv = (const float*)d_in[3];
    const float* Wo = (const float*)d_in[4];
    const float* bo = (const float*)d_in[5];
    // d_in[6] = causal mask — recomputed from indices, not read.

    const size_t elems  = (size_t)M_TOTAL * D_MODEL;   // 4194304
    const size_t welems = (size_t)D_MODEL * D_MODEL;   // 1048576
    __bf16* xb  = (__bf16*)d_ws;       // seg0: x (bf16) -> later Cc (aliased)
    __bf16* Qb  = xb + elems;
    __bf16* Kb  = Qb + elems;
    __bf16* Vtg = Kb + elems;          // [32][64][2048]  (V^T)
    __bf16* Wqb = Vtg + elems;
    __bf16* Wkb = Wqb + welems;
    __bf16* Wvb = Wkb + welems;
    __bf16* Wob = Wvb + welems;        // end: 40 MB
    __bf16* Cc  = xb;

    // 0) all fp32 -> bf16 conversions in one launch
    convert_all<<<dim3(4096), 256, 0, stream>>>(
        x, Wq, Wk, Wv, Wo, xb, Wqb, Wkb, Wvb, Wob);

    // 1) QKV projections (Q pre-scaled by 0.125*log2e), dbuf prefetch loop
    qkv_kernel<<<dim3(M_TOTAL / 128, 3 * D_MODEL / 128), 256, 0, stream>>>(
        xb, Wqb, Wkb, Wvb, Qb, Kb, Vtg);

    // 2) causal flash attention: 8-wave blocks, QBLK=128
    attn_kernel<<<dim3(BATCH * NUM_HEADS, 16), 512, 0, stream>>>(
        Qb, Kb, Vtg, Cc);

    // 3) output projection + bias -> fp32 out (64x64 tiles, dbuf prefetch)
    oproj_kernel<<<dim3(M_TOTAL / 64, D_MODEL / 64), 256, 0, stream>>>(
        Cc, Wob, bo, (float*)d_out);
}

// Round 16
// 179.292 us; speedup vs baseline: 1.0263x; 1.0263x over previous
//
#include <hip/hip_runtime.h>
#include <hip/hip_bf16.h>
#include <stdint.h>

typedef __bf16 bf16x8 __attribute__((ext_vector_type(8)));
typedef __bf16 bf16x4 __attribute__((ext_vector_type(4)));
typedef float  f32x4  __attribute__((ext_vector_type(4)));
typedef unsigned int u32x4 __attribute__((ext_vector_type(4)));

#define D_MODEL 1024
#define NUM_HEADS 16
#define D_K 64
#define BATCH 2
#define SEQ 2048
#define M_TOTAL (BATCH * SEQ)   // 4096

// 0.125 (1/sqrt(64)) * log2(e): folded into Q at the qkv epilogue so the
// attention softmax is a bare exp2 (v_exp_f32), no per-element scale mul.
#define Q_SCALE 0.18033688011112042f

static __device__ __forceinline__ bf16x8 load8(const __bf16* p) {
    return *reinterpret_cast<const bf16x8*>(p);
}

#define MFMA16(a, b, c) __builtin_amdgcn_mfma_f32_16x16x32_bf16((a), (b), (c), 0, 0, 0)

// Async global->LDS, 16B per lane. LDS dest = wave-uniform base + lane*16.
static __device__ __forceinline__ void gload16(const void* g, const void* lds) {
    __builtin_amdgcn_global_load_lds(
        (const __attribute__((address_space(1))) uint32_t*)g,
        (__attribute__((address_space(3))) uint32_t*)lds,
        16, 0, 0);
}

// Pack two f32 -> one u32 of 2 bf16 (lo = first arg). No builtin on gfx950.
static __device__ __forceinline__ uint32_t cvtpk(float lo, float hi) {
    uint32_t r;
    asm("v_cvt_pk_bf16_f32 %0, %1, %2" : "=v"(r) : "v"(lo), "v"(hi));
    return r;
}
// CDNA4 zip semantics ("DST rows 2:3 <-> SRC rows 0:1", rows = 16 lanes):
//   swap32: a' = (a@q0, a@q1, b@q0, b@q1), b' = (a@q2, a@q3, b@q2, b@q3)
static __device__ __forceinline__ void swap32(uint32_t& a, uint32_t& b) {
    asm("v_permlane32_swap_b32 %0, %1" : "+v"(a), "+v"(b));
}
// swap16 ("DST odd rows <-> SRC even rows"):
//   a' = (a@q0, b@q0, a@q2, b@q2), b' = (a@q1, b@q1, a@q3, b@q3)
static __device__ __forceinline__ void swap16(uint32_t& a, uint32_t& b) {
    asm("v_permlane16_swap_b32 %0, %1" : "+v"(a), "+v"(b));
}

// ---------------------------------------------------------------------------
// One launch: x (2048 blocks) + 4 weight matrices (512 blocks each) fp32->bf16.
// ---------------------------------------------------------------------------
__global__ __launch_bounds__(256) void convert_all(
    const float* __restrict__ X,
    const float* __restrict__ Wq, const float* __restrict__ Wk,
    const float* __restrict__ Wv, const float* __restrict__ Wo,
    __bf16* __restrict__ xb,
    __bf16* __restrict__ dq, __bf16* __restrict__ dk,
    __bf16* __restrict__ dv, __bf16* __restrict__ dw)
{
    const float* src; __bf16* dst; size_t idx;
    if (blockIdx.x < 2048) {
        src = X; dst = xb;
        idx = (size_t)blockIdx.x * 256 + threadIdx.x;
    } else {
        const int wb  = blockIdx.x - 2048;
        const int sel = wb >> 9;
        src = (sel == 0) ? Wq : (sel == 1) ? Wk : (sel == 2) ? Wv : Wo;
        dst = (sel == 0) ? dq : (sel == 1) ? dk : (sel == 2) ? dv : dw;
        idx = (size_t)(wb & 511) * 256 + threadIdx.x;
    }
    const f32x4 a = *reinterpret_cast<const f32x4*>(src + idx * 8);
    const f32x4 b = *reinterpret_cast<const f32x4*>(src + idx * 8 + 4);
    bf16x8 r;
#pragma unroll
    for (int e = 0; e < 4; e++) { r[e] = (__bf16)a[e]; r[4 + e] = (__bf16)b[e]; }
    *reinterpret_cast<bf16x8*>(dst + idx * 8) = r;
}

// ---------------------------------------------------------------------------
// QKV GEMM (R16 config): 128x128 tile, BK=64, swizzled gload16 staging,
// double-buffered prefetch loop (one barrier per K-step, next tile's loads
// in flight through compute). LDS 64 KB -> 2 blocks/CU. Q output pre-scaled
// by Q_SCALE. V transposed through LDS -> V^T. grid = (32, 24), block = 256.
// ---------------------------------------------------------------------------
__global__ __launch_bounds__(256) void qkv_kernel(
    const __bf16* __restrict__ Xb,
    const __bf16* __restrict__ Wqb,
    const __bf16* __restrict__ Wkb,
    const __bf16* __restrict__ Wvb,
    __bf16* __restrict__ Qb,
    __bf16* __restrict__ Kb,
    __bf16* __restrict__ Vtg)
{
    __shared__ alignas(16) char smem[65536];   // A[2]16K + B[2]16K; V scratch 34K
    __bf16* As0 = (__bf16*)smem;               // [2][128*64], chunk-swizzled
    __bf16* Bs0 = As0 + 2 * 128 * 64;

    const int lane = threadIdx.x & 63;
    const int wid  = threadIdx.x >> 6;
    const int m    = lane & 15;
    const int quad = lane >> 4;
    const int wrow = wid >> 1, wcol = wid & 1;
    const int row0 = blockIdx.x * 128;
    const int col0 = blockIdx.y * 128;
    const int wsel = col0 >> 10;
    const int lcol0 = col0 & 1023;

    const __bf16* W = (wsel == 0) ? Wqb : (wsel == 1) ? Wkb : Wvb;

    // staging: 128x64 A-tile + 128x64 B-tile into buffer `buf`
    auto stage = [&](int k0, int buf) {
#pragma unroll
        for (int i = 0; i < 4; i++) {
            const int slot = wid * 256 + i * 64 + lane;
            const int row  = slot >> 3;
            const int cg   = (slot & 7) ^ (row & 7);
            gload16(Xb + (size_t)(row0 + row) * D_MODEL + k0 + cg * 8,
                    (const char*)(As0 + buf * 8192) + (size_t)(wid * 256 + i * 64) * 16);
            gload16(W + (size_t)(lcol0 + row) * D_MODEL + k0 + cg * 8,
                    (const char*)(Bs0 + buf * 8192) + (size_t)(wid * 256 + i * 64) * 16);
        }
    };

    f32x4 acc[4][4];
#pragma unroll
    for (int i = 0; i < 4; i++)
#pragma unroll
        for (int j = 0; j < 4; j++) acc[i][j] = (f32x4){0.f, 0.f, 0.f, 0.f};

    stage(0, 0);
    int cur = 0;
#pragma unroll 1
    for (int k0 = 0; k0 < D_MODEL; k0 += 64) {
        __syncthreads();                       // buffer `cur` staged
        if (k0 + 64 < D_MODEL) stage(k0 + 64, cur ^ 1);   // in flight through
                                                          // compute below
        const __bf16* As = As0 + cur * 8192;
        const __bf16* Bs = Bs0 + cur * 8192;

        bf16x8 a2[2][4], b2[2][4];
#pragma unroll
        for (int ks = 0; ks < 2; ks++) {
#pragma unroll
            for (int i = 0; i < 4; i++) {
                const int rA = wrow * 64 + i * 16 + m;
                a2[ks][i] = load8(As + rA * 64 + (((ks * 4 + quad) ^ (rA & 7)) * 8));
                const int rB = wcol * 64 + i * 16 + m;
                b2[ks][i] = load8(Bs + rB * 64 + (((ks * 4 + quad) ^ (rB & 7)) * 8));
            }
        }
#pragma unroll
        for (int ks = 0; ks < 2; ks++)
#pragma unroll
            for (int i = 0; i < 4; i++)
#pragma unroll
                for (int j = 0; j < 4; j++)
                    acc[i][j] = MFMA16(a2[ks][i], b2[ks][j], acc[i][j]);
        cur ^= 1;
    }
    __syncthreads();   // all LDS reads done before V-path smem reuse

    if (wsel < 2) {
        // Q (pre-scaled) / K: [bh][s][dk]
        __bf16* Out = wsel ? Kb : Qb;
        const float sc = wsel ? 1.f : Q_SCALE;
#pragma unroll
        for (int i = 0; i < 4; i++) {
#pragma unroll
            for (int r = 0; r < 4; r++) {
                const int R  = row0 + wrow * 64 + i * 16 + quad * 4 + r;
                const int bb = R >> 11;
                const int s  = R & (SEQ - 1);
#pragma unroll
                for (int j = 0; j < 4; j++) {
                    const int e  = lcol0 + wcol * 64 + j * 16 + m;
                    const int h  = e >> 6;
                    const int dk = e & (D_K - 1);
                    Out[((size_t)(bb * NUM_HEADS + h) * SEQ + s) * D_K + dk] =
                        (__bf16)(acc[i][j][r] * sc);
                }
            }
        }
    } else {
        // V: transpose tile through LDS, store coalesced V^T rows.
        __bf16* Ls = (__bf16*)smem;   // [128][136]
#pragma unroll
        for (int i = 0; i < 4; i++)
#pragma unroll
            for (int r = 0; r < 4; r++)
#pragma unroll
                for (int j = 0; j < 4; j++)
                    Ls[(wcol * 64 + j * 16 + m) * 136 +
                       wrow * 64 + i * 16 + quad * 4 + r] = (__bf16)acc[i][j][r];
        __syncthreads();
        const int bb   = row0 >> 11;
        const int sloc = row0 & (SEQ - 1);
#pragma unroll
        for (int i = 0; i < 8; i++) {
            const int c   = i * 256 + threadIdx.x;
            const int dkl = c >> 4;
            const int sc  = c & 15;
            const bf16x8 v = load8(Ls + dkl * 136 + sc * 8);
            const int e  = lcol0 + dkl;
            const int h  = e >> 6;
            const int dk = e & (D_K - 1);
            const int bh = bb * NUM_HEADS + h;
            *reinterpret_cast<bf16x8*>(
                Vtg + ((size_t)bh * D_K + dk) * SEQ + sloc + sc * 8) = v;
        }
    }
}

// ---------------------------------------------------------------------------
// Flash attention, causal. R25: T4 COUNTED-VMCNT pipeline on the R22
// structure. 3 staging buffers; prologue issues tiles 0,1; iteration t
// issues tile t+2. The __syncthreads (implicit vmcnt(0) drain of the
// JUST-ISSUED prefetch) is replaced by: s_waitcnt vmcnt(2) (tile t's 2
// gload16s complete -- they were issued TWO compute phases ago; tile t+1's
// 2 stay in flight) + raw s_barrier + sched_barrier(0). vmcnt(0) only on
// the final iteration. Race-safety: buffer (t+2)%3 was last READ in
// iteration t-1, and each wave's reads completed (own lgkmcnt before MFMA)
// before it reaches iteration t's barrier -> write-after-read safe.
// Q-load wait pinned OUTSIDE the loop via a touch-asm on the Q registers.
// Everything else identical to R22 (8-wave blocks, QBLK=128, 512 blocks,
// register-P zip-permlane, ones-MFMA row sums). LDS 48 KB -> 2 blocks/CU.
// ---------------------------------------------------------------------------
__global__ __launch_bounds__(512) void attn_kernel(
    const __bf16* __restrict__ Qb,
    const __bf16* __restrict__ Kb,
    const __bf16* __restrict__ Vtg,
    __bf16* __restrict__ Cc)
{
    __shared__ alignas(16) __bf16 Ks[3][64 * 64];  // 3-deep, 24 KB
    __shared__ alignas(16) __bf16 Vt[3][64 * 64];  // 3-deep, 24 KB

    const int lane = threadIdx.x & 63;
    const int wid  = threadIdx.x >> 6;             // 0..7
    const int m    = lane & 15;
    const int quad = lane >> 4;
    const int bh   = blockIdx.x;
    const int b    = bh >> 4;
    const int h    = bh & (NUM_HEADS - 1);
    const int sp   = 15 - blockIdx.y;              // 128-row strip, big first

    const __bf16* Qp = Qb  + (size_t)bh * SEQ * D_K;
    const __bf16* Kp = Kb  + (size_t)bh * SEQ * D_K;
    const __bf16* Vp = Vtg + (size_t)bh * D_K * SEQ;

    // staging: 64x64 K tile + 64x64 V^T tile; 512 threads cover each 8 KB
    // tile in ONE gload16 per thread per operand (2 vmem instrs per wave).
    auto stage = [&](int k0, int buf) {
        const int slot = wid * 64 + lane;
        const int row  = slot >> 3;
        const int cg   = (slot & 7) ^ (row & 7);
        gload16(Kp + (size_t)(k0 + row) * D_K + cg * 8,
                (const char*)&Ks[buf][0] + (size_t)slot * 16);
        gload16(Vp + (size_t)row * SEQ + k0 + cg * 8,
                (const char*)&Vt[buf][0] + (size_t)slot * 16);
    };

    bf16x8 vone;
#pragma unroll
    for (int e = 0; e < 8; e++) vone[e] = (__bf16)1.0f;

    const int q0     = sp * 128 + wid * 16;        // this wave's 16 q rows
    const int myDiag = q0 >> 6;                    // wave's diagonal tile
    const int T      = 2 * sp + 2;                 // tiles for this strip (>=2)

    const bf16x8 qB0 = load8(Qp + (size_t)(q0 + m) * D_K + quad * 8);
    const bf16x8 qB1 = load8(Qp + (size_t)(q0 + m) * D_K + 32 + quad * 8);
    // Pin the compiler's vmcnt wait for the Q loads HERE (outside the loop),
    // so no vmcnt(0)-ish wait lands inside the pipelined loop body.
    {
        const u32x4 t0 = __builtin_bit_cast(u32x4, qB0);
        const u32x4 t1 = __builtin_bit_cast(u32x4, qB1);
        asm volatile("" :: "v"(t0[0]), "v"(t0[1]), "v"(t0[2]), "v"(t0[3]),
                           "v"(t1[0]), "v"(t1[1]), "v"(t1[2]), "v"(t1[3]));
    }

    f32x4 oacc[4];
#pragma unroll
    for (int c = 0; c < 4; c++) oacc[c] = (f32x4){0.f, 0.f, 0.f, 0.f};
    f32x4 accL = (f32x4){0.f, 0.f, 0.f, 0.f};      // l for q = q0+quad*4+r

    stage(0, 0);
    stage(64, 1);                  // T >= 2 always; tile 1 in-bounds
    int bi = 0;                    // buffer holding tile t
#pragma unroll 1
    for (int t = 0; t < T; t++) {
        // counted drain: tile t's loads (issued 2 phases ago) must be done;
        // tile t+1's 2 loads may remain in flight. Last iter: drain all.
        if (t + 1 < T) {
            asm volatile("s_waitcnt vmcnt(2)" ::: "memory");
        } else {
            asm volatile("s_waitcnt vmcnt(0)" ::: "memory");
        }
        __builtin_amdgcn_s_barrier();
        __builtin_amdgcn_sched_barrier(0);

        if (t + 2 < T) {
            int b2 = bi + 2; if (b2 >= 3) b2 -= 3;
            stage((t + 2) * 64, b2);           // in flight through compute
        }

        if (t <= myDiag) {
            const bool diag = (t == myDiag);
            const int  k0   = t * 64;
            const __bf16* Kc = &Ks[bi][0];
            const __bf16* Vc = &Vt[bi][0];

            // ---- S^T = K Q^T (rows=keys, cols=q); exp2; pack to bf16.
            // Lane (m,quad) produces keys {kb*16+quad*4 .. +3} for q=q0+m:
            // w0[kb] = keys {4*quad, 4*quad+1}, w1[kb] = {+2, +3}.
            uint32_t w0[4], w1[4];
#pragma unroll
            for (int kb = 0; kb < 4; kb++) {
                const int rK = kb * 16 + m;
                const bf16x8 kfA = load8(Kc + rK * 64 + ((quad ^ (rK & 7)) * 8));
                const bf16x8 kfB = load8(Kc + rK * 64 + (((quad + 4) ^ (rK & 7)) * 8));
                f32x4 st = (f32x4){0.f, 0.f, 0.f, 0.f};
                st = MFMA16(kfA, qB0, st);
                st = MFMA16(kfB, qB1, st);
                const int q    = q0 + m;
                const int keyb = k0 + kb * 16 + quad * 4;
                float ex[4];
#pragma unroll
                for (int r = 0; r < 4; r++) {
                    float e = __builtin_amdgcn_exp2f(st[r]);
                    if (diag) e = (keyb + r <= q) ? e : 0.f;
                    ex[r] = e;
                }
                w0[kb] = cvtpk(ex[0], ex[1]);
                w1[kb] = cvtpk(ex[2], ex[3]);
            }

            // ---- redistribute to A-fragments (keys 8*quad..+7 per lane).
            // Zip semantics, verified key-by-key:
            //   (X=w[lo], Y=w[hi]); swap32; swap16 => X=word j, Y=word j+2.
            uint32_t pa0 = w0[0], pa2 = w0[1]; swap32(pa0, pa2); swap16(pa0, pa2);
            uint32_t pa1 = w1[0], pa3 = w1[1]; swap32(pa1, pa3); swap16(pa1, pa3);
            uint32_t pb0 = w0[2], pb2 = w0[3]; swap32(pb0, pb2); swap16(pb0, pb2);
            uint32_t pb1 = w1[2], pb3 = w1[3]; swap32(pb1, pb3); swap16(pb1, pb3);
            const u32x4 ua = (u32x4){pa0, pa1, pa2, pa3};
            const u32x4 ub = (u32x4){pb0, pb1, pb2, pb3};
            const bf16x8 pfA = __builtin_bit_cast(bf16x8, ua);
            const bf16x8 pfB = __builtin_bit_cast(bf16x8, ub);

            // ---- row-sum via ones-MFMA: accL[r] = sum_k P[q=quad*4+r][k]
            accL = MFMA16(pfA, vone, accL);
            accL = MFMA16(pfB, vone, accL);

            // ---- P.V ----
#pragma unroll
            for (int c = 0; c < 4; c++) {
                const int rV = c * 16 + m;
                const bf16x8 vfA = load8(Vc + rV * 64 + ((quad ^ (rV & 7)) * 8));
                const bf16x8 vfB = load8(Vc + rV * 64 + (((quad + 4) ^ (rV & 7)) * 8));
                oacc[c] = MFMA16(pfA, vfA, oacc[c]);
                oacc[c] = MFMA16(pfB, vfB, oacc[c]);
            }
        }
        bi = (bi == 2) ? 0 : bi + 1;
    }

    // ---- epilogue: l is already per-register in accL ----
#pragma unroll
    for (int r = 0; r < 4; r++) {
        const float inv = 1.f / accL[r];
        const int srow = q0 + quad * 4 + r;
#pragma unroll
        for (int c = 0; c < 4; c++) {
            const size_t o2 = ((size_t)(b * SEQ + srow)) * D_MODEL + h * D_K + c * 16 + m;
            Cc[o2] = (__bf16)(oacc[c][r] * inv);
        }
    }
}

// ---------------------------------------------------------------------------
// Output projection (R16 config): Out = Cc * Wo^T + bo (fp32). 64x64 tile,
// grid (64,16) = 1024 blocks = 4/CU, double-buffered prefetch loop (one
// barrier per K-step), both operands via gload16 (bf16).
// ---------------------------------------------------------------------------
__global__ __launch_bounds__(256) void oproj_kernel(
    const __bf16* __restrict__ Cc,
    const __bf16* __restrict__ Wob,
    const float* __restrict__ bo,
    float* __restrict__ Out)
{
    __shared__ alignas(16) __bf16 As[2][64 * 64];  // ping-pong, 8 KB each
    __shared__ alignas(16) __bf16 Bs[2][64 * 64];  // ping-pong, 8 KB each

    const int lane = threadIdx.x & 63;
    const int wid  = threadIdx.x >> 6;
    const int m    = lane & 15;
    const int quad = lane >> 4;
    const int wrow = wid >> 1, wcol = wid & 1;
    const int row0 = blockIdx.x * 64;
    const int col0 = blockIdx.y * 64;

    auto stage = [&](int k0, int buf) {
#pragma unroll
        for (int i = 0; i < 2; i++) {
            const int slot = wid * 128 + i * 64 + lane;
            const int row  = slot >> 3;
            const int cg   = (slot & 7) ^ (row & 7);
            gload16(Cc + (size_t)(row0 + row) * D_MODEL + k0 + cg * 8,
                    (const char*)&As[buf][0] + (size_t)slot * 16);
            gload16(Wob + (size_t)(col0 + row) * D_MODEL + k0 + cg * 8,
                    (const char*)&Bs[buf][0] + (size_t)slot * 16);
        }
    };

    f32x4 acc[2][2];
#pragma unroll
    for (int i = 0; i < 2; i++)
#pragma unroll
        for (int j = 0; j < 2; j++) acc[i][j] = (f32x4){0.f, 0.f, 0.f, 0.f};

    stage(0, 0);
    int cur = 0;
#pragma unroll 1
    for (int k0 = 0; k0 < D_MODEL; k0 += 64) {
        __syncthreads();                       // buffer `cur` staged
        if (k0 + 64 < D_MODEL) stage(k0 + 64, cur ^ 1);

        bf16x8 a2[2][2], b2[2][2];
#pragma unroll
        for (int ks = 0; ks < 2; ks++) {
#pragma unroll
            for (int i = 0; i < 2; i++) {
                const int rA = wrow * 32 + i * 16 + m;
                a2[ks][i] = load8(&As[cur][0] + rA * 64 + (((ks * 4 + quad) ^ (rA & 7)) * 8));
                const int rB = wcol * 32 + i * 16 + m;
                b2[ks][i] = load8(&Bs[cur][0] + rB * 64 + (((ks * 4 + quad) ^ (rB & 7)) * 8));
            }
        }
#pragma unroll
        for (int ks = 0; ks < 2; ks++)
#pragma unroll
            for (int i = 0; i < 2; i++)
#pragma unroll
                for (int j = 0; j < 2; j++)
                    acc[i][j] = MFMA16(a2[ks][i], b2[ks][j], acc[i][j]);
        cur ^= 1;
    }

#pragma unroll
    for (int i = 0; i < 2; i++) {
#pragma unroll
        for (int r = 0; r < 4; r++) {
            const int R = row0 + wrow * 32 + i * 16 + quad * 4 + r;
#pragma unroll
            for (int j = 0; j < 2; j++) {
                const int E = col0 + wcol * 32 + j * 16 + m;
                Out[(size_t)R * D_MODEL + E] = acc[i][j][r] + bo[E];
            }
        }
    }
}

// ---------------------------------------------------------------------------
extern "C" void kernel_launch(void* const* d_in, const int* in_sizes, int n_in,
                              void* d_out, int out_size, void* d_ws, size_t ws_size,
                              hipStream_t stream) {
    const float* x  = (const float*)d_in[0];
    const float* Wq = (const float*)d_in[1];
    const float* Wk = (const float*)d_in[2];
    const float* Wv = (const float*)d_in[3];
    const float* Wo = (const float*)d_in[4];
    const float* bo = (const float*)d_in[5];
    // d_in[6] = causal mask — recomputed from indices, not read.

    const size_t elems  = (size_t)M_TOTAL * D_MODEL;   // 4194304
    const size_t welems = (size_t)D_MODEL * D_MODEL;   // 1048576
    __bf16* xb  = (__bf16*)d_ws;       // seg0: x (bf16) -> later Cc (aliased)
    __bf16* Qb  = xb + elems;
    __bf16* Kb  = Qb + elems;
    __bf16* Vtg = Kb + elems;          // [32][64][2048]  (V^T)
    __bf16* Wqb = Vtg + elems;
    __bf16* Wkb = Wqb + welems;
    __bf16* Wvb = Wkb + welems;
    __bf16* Wob = Wvb + welems;        // end: 40 MB
    __bf16* Cc  = xb;

    // 0) all fp32 -> bf16 conversions in one launch
    convert_all<<<dim3(4096), 256, 0, stream>>>(
        x, Wq, Wk, Wv, Wo, xb, Wqb, Wkb, Wvb, Wob);

    // 1) QKV projections (Q pre-scaled by 0.125*log2e), dbuf prefetch loop
    qkv_kernel<<<dim3(M_TOTAL / 128, 3 * D_MODEL / 128), 256, 0, stream>>>(
        xb, Wqb, Wkb, Wvb, Qb, Kb, Vtg);

    // 2) causal flash attention: 8-wave blocks, 3-deep counted-vmcnt pipeline
    attn_kernel<<<dim3(BATCH * NUM_HEADS, 16), 512, 0, stream>>>(
        Qb, Kb, Vtg, Cc);

    // 3) output projection + bias -> fp32 out (64x64 tiles, dbuf prefetch)
    oproj_kernel<<<dim3(M_TOTAL / 64, D_MODEL / 64), 256, 0, stream>>>(
        Cc, Wob, bo, (float*)d_out);
}